// Round 8
// baseline (156.964 us; speedup 1.0000x reference)
//
#include <hip/hip_runtime.h>
#include <stdint.h>

#define TT 2048
#define BB 2
#define MROWS (BB*TT)
#define LSCALE 0.18033688011112043f   // 0.125 * log2(e)

typedef unsigned short u16;
typedef __bf16 bf16x8 __attribute__((ext_vector_type(8)));
typedef float f32x4 __attribute__((ext_vector_type(4)));
typedef short s16x8 __attribute__((ext_vector_type(8)));
typedef unsigned short u16x4 __attribute__((ext_vector_type(4)));

#define GLOBAL_AS const __attribute__((address_space(1))) void*
#define LDS_AS __attribute__((address_space(3))) void*

__device__ __forceinline__ u16 f2b(float f){
  uint32_t u = __builtin_bit_cast(uint32_t, f);
  u = (u + 0x7FFFu + ((u >> 16) & 1u)) >> 16;
  return (u16)u;
}

// ---------------- prep kernels ----------------
__global__ void cvt_bf16(const float* __restrict__ in, u16* __restrict__ out, int n4){
  int i = blockIdx.x * 256 + threadIdx.x;
  if (i < n4){
    float4 v = ((const float4*)in)[i];
    u16x4 o; o.x = f2b(v.x); o.y = f2b(v.y); o.z = f2b(v.z); o.w = f2b(v.w);
    ((u16x4*)out)[i] = o;
  }
}

// Wqc[d][h*64+lc] = sum_dd Wq[d][h*64+dd] * Wc[dd][lc]  (fold Wc into Wq)
// block 256 additionally builds bqc (folded bias).
__global__ __launch_bounds__(256) void build_wqc(const float* __restrict__ Wq,
                                                 const float* __restrict__ Wc,
                                                 const float* __restrict__ bq,
                                                 float* __restrict__ Wqc,
                                                 float* __restrict__ bqc){
  __shared__ float wc[4096];
  const int t = threadIdx.x;
  #pragma unroll
  for (int i = 0; i < 16; ++i) wc[i * 256 + t] = Wc[i * 256 + t];
  __syncthreads();
  if (blockIdx.x == 256){
    #pragma unroll
    for (int i = 0; i < 4; ++i){
      int nn = t * 4 + i;
      int h = nn >> 6, lc = nn & 63;
      float acc = 0.f;
      #pragma unroll
      for (int dd = 0; dd < 64; ++dd) acc += bq[h * 64 + dd] * wc[dd * 64 + lc];
      bqc[nn] = acc;
    }
    return;
  }
  const int idx = blockIdx.x * 256 + t;   // [0, 65536)
  const int d = idx >> 6;
  const int h = (idx >> 2) & 15;
  const int lq = idx & 3;
  float wqr[64];
  const float4* wq4 = (const float4*)(Wq + (size_t)d * 1024 + h * 64);
  #pragma unroll
  for (int i = 0; i < 16; ++i){
    float4 v = wq4[i];
    wqr[i * 4 + 0] = v.x; wqr[i * 4 + 1] = v.y; wqr[i * 4 + 2] = v.z; wqr[i * 4 + 3] = v.w;
  }
  float* outp = Wqc + (size_t)d * 1024 + h * 64 + lq * 16;
  #pragma unroll
  for (int j = 0; j < 16; ++j){
    int lc = lq * 16 + j;
    float acc = 0.f;
    #pragma unroll
    for (int dd = 0; dd < 64; ++dd) acc += wqr[dd] * wc[dd * 64 + lc];
    outp[j] = acc;
  }
}

// all four 1024x1024 weight transposes (f32 -> bf16, out[c][r] = in[r][c]) in one dispatch
__global__ void transpose_w4(const float* __restrict__ s0, const float* __restrict__ s1,
                             const float* __restrict__ s2, const float* __restrict__ s3,
                             u16* __restrict__ o0, u16* __restrict__ o1,
                             u16* __restrict__ o2, u16* __restrict__ o3){
  const int z = blockIdx.z;
  const float* in = (z == 0) ? s0 : (z == 1) ? s1 : (z == 2) ? s2 : s3;
  u16* out = (z == 0) ? o0 : (z == 1) ? o1 : (z == 2) ? o2 : o3;
  __shared__ float t[32][33];
  int tx = threadIdx.x & 31, ty = threadIdx.x >> 5;
  int c0 = blockIdx.x * 32, r0 = blockIdx.y * 32;
  #pragma unroll
  for (int i = 0; i < 32; i += 8)
    t[ty + i][tx] = in[(size_t)(r0 + ty + i) * 1024 + c0 + tx];
  __syncthreads();
  #pragma unroll
  for (int i = 0; i < 32; i += 8)
    out[(size_t)(c0 + ty + i) * 1024 + r0 + tx] = f2b(t[tx][ty + i]);
}

// vt[bh][d][s] = vb[b*T + s][h*64 + d]   (bf16 -> bf16 transpose per head)
__global__ void transpose_v(const u16* __restrict__ vb, u16* __restrict__ vt){
  __shared__ u16 t[32][34];
  int tx = threadIdx.x & 31, ty = threadIdx.x >> 5;
  int s0 = blockIdx.x * 32, d0 = blockIdx.y * 32, bh = blockIdx.z;
  int b = bh >> 4, h = bh & 15;
  #pragma unroll
  for (int i = 0; i < 32; i += 8)
    t[ty + i][tx] = vb[(size_t)(b * TT + s0 + ty + i) * 1024 + h * 64 + d0 + tx];
  __syncthreads();
  #pragma unroll
  for (int i = 0; i < 32; i += 8)
    vt[((size_t)bh * 64 + d0 + ty + i) * TT + s0 + tx] = t[tx][ty + i];
}

// ---------------- 128x128 bf16 MFMA GEMM tile (m97 structure) ----------------
__device__ __forceinline__ void gemm_tile(const u16* __restrict__ A, const u16* __restrict__ BT,
                                          int m0, int n0, int K, f32x4 (&acc)[4][4],
                                          u16* As, u16* Bs, int tid){
  const int wv = tid >> 6, l = tid & 63;
  const int aoff = ((wv >> 1) * 64 + (l & 15)) * 32 + ((l >> 4) << 3);
  const int boff = ((wv & 1) * 64 + (l & 15)) * 32 + ((l >> 4) << 3);
  const int ob0 = wv * 1024 + l * 16;           // byte offset in 8KB tile
  for (int kt = 0; kt < K; kt += 32){
    __syncthreads();
    #pragma unroll
    for (int j = 0; j < 2; ++j){
      int ob = ob0 + j * 4096;
      int row = ob >> 6, col = (ob & 63) >> 1;  // col in elements (mult of 8)
      __builtin_amdgcn_global_load_lds((GLOBAL_AS)(A + (size_t)(m0 + row) * 1024 + kt + col),
                                       (LDS_AS)(As + wv * 512 + j * 2048), 16, 0, 0);
      __builtin_amdgcn_global_load_lds((GLOBAL_AS)(BT + (size_t)(n0 + row) * 1024 + kt + col),
                                       (LDS_AS)(Bs + wv * 512 + j * 2048), 16, 0, 0);
    }
    __syncthreads();
    bf16x8 av[4], bw[4];
    #pragma unroll
    for (int m = 0; m < 4; ++m) av[m] = *(const bf16x8*)(As + aoff + m * 512);
    #pragma unroll
    for (int n = 0; n < 4; ++n) bw[n] = *(const bf16x8*)(Bs + boff + n * 512);
    #pragma unroll
    for (int m = 0; m < 4; ++m)
      #pragma unroll
      for (int n = 0; n < 4; ++n)
        acc[m][n] = __builtin_amdgcn_mfma_f32_16x16x32_bf16(av[m], bw[n], acc[m][n], 0, 0, 0);
  }
}

__global__ __launch_bounds__(256) void gemm_qkv(
    const u16* __restrict__ xb,
    const u16* __restrict__ W0T, const u16* __restrict__ W1T, const u16* __restrict__ W2T,
    const float* __restrict__ b0, const float* __restrict__ b1, const float* __restrict__ b2,
    u16* __restrict__ o0, u16* __restrict__ o1, u16* __restrict__ o2){
  __shared__ u16 As[4096], Bs[4096];
  const int z = blockIdx.z;
  const u16* BT = (z == 0) ? W0T : (z == 1) ? W1T : W2T;
  const float* bias = (z == 0) ? b0 : (z == 1) ? b1 : b2;
  u16* Out = (z == 0) ? o0 : (z == 1) ? o1 : o2;
  const float osc = (z == 0) ? LSCALE : 1.0f;   // fold softmax scale into Q
  const int n0 = blockIdx.x * 128, m0 = blockIdx.y * 128;
  const int tid = threadIdx.x, wv = tid >> 6, l = tid & 63;
  f32x4 acc[4][4] = {};
  gemm_tile(xb, BT, m0, n0, 1024, acc, As, Bs, tid);
  const int wr = wv >> 1, wc = wv & 1;
  #pragma unroll
  for (int n = 0; n < 4; ++n){
    int col = n0 + wc * 64 + n * 16 + (l & 15);
    float bb = bias[col];
    #pragma unroll
    for (int m = 0; m < 4; ++m){
      int r0 = m0 + wr * 64 + m * 16 + ((l >> 4) << 2);
      #pragma unroll
      for (int r = 0; r < 4; ++r)
        Out[(size_t)(r0 + r) * 1024 + col] = f2b((acc[m][n][r] + bb) * osc);
    }
  }
}

__global__ __launch_bounds__(256) void gemm_fp32out(
    const u16* __restrict__ A, const u16* __restrict__ BT,
    const float* __restrict__ bias, float* __restrict__ Out){
  __shared__ u16 As[4096], Bs[4096];
  const int n0 = blockIdx.x * 128, m0 = blockIdx.y * 128;
  const int tid = threadIdx.x, wv = tid >> 6, l = tid & 63;
  f32x4 acc[4][4] = {};
  gemm_tile(A, BT, m0, n0, 1024, acc, As, Bs, tid);
  const int wr = wv >> 1, wc = wv & 1;
  #pragma unroll
  for (int n = 0; n < 4; ++n){
    int col = n0 + wc * 64 + n * 16 + (l & 15);
    float bb = bias[col];
    #pragma unroll
    for (int m = 0; m < 4; ++m){
      int r0 = m0 + wr * 64 + m * 16 + ((l >> 4) << 2);
      #pragma unroll
      for (int r = 0; r < 4; ++r)
        Out[(size_t)(r0 + r) * 1024 + col] = acc[m][n][r] + bb;
    }
  }
}

// ---------------- flash attention (causal, per (b,h)) ----------------
// Fully decoupled waves: 1 wave per block (64 thr), each wave owns 32 q-rows
// (2 q-frag sets sharing every K/V fetch). K/V fragments gathered DIRECTLY
// from global (L2-resident: 4 heads per XCD) with the exact MFMA lane mapping
// -> zero barriers, zero vmcnt drains, no LDS staging. P round-trips through
// 4KB wave-private LDS (XOR-swizzled dwords). grid 2048: bh = idx&31 (XCD
// locality), q-group heavy-first.
__global__ __launch_bounds__(64, 3) void attn(
    const u16* __restrict__ qcg, const u16* __restrict__ kg,
    const u16* __restrict__ vtg, u16* __restrict__ yg){
  __shared__ u16 Ps[2][1024];           // [set][16 q-rows x 64 s]
  const int idx = blockIdx.x;
  const int bh = idx & 31;
  const int qg = 63 - (idx >> 5);       // q-group of 32 rows, heavy-first
  const int b = bh >> 4, h = bh & 15;
  const int q0 = qg * 32;
  const int l = threadIdx.x & 63;
  const int c4 = l >> 4, q16 = l & 15;
  const size_t base = (size_t)b * TT * 1024 + h * 64;
  const u16* Q = qcg + base;
  const u16* K = kg + base;
  const u16* Vt = vtg + (size_t)bh * 64 * TT;     // [64 d][T s]

  // Q fragments: 2 sets x 16 q-rows (B-operand: col=q at l&15)
  bf16x8 qf[2][2];
  #pragma unroll
  for (int qs = 0; qs < 2; ++qs){
    int qr = q0 + qs * 16 + q16;
    #pragma unroll
    for (int ks = 0; ks < 2; ++ks)
      qf[qs][ks] = *(const bf16x8*)(Q + (size_t)qr * 1024 + ks * 32 + c4 * 8);
  }
  f32x4 yacc[2][4] = {};
  float mrow[2] = {-1e30f, -1e30f}, srow[2] = {0.f, 0.f};

  const int pm = (q16 & 7) << 2;        // Ps dword-col XOR mask

  const int nt = (qg >> 1) + 1;         // tiles of BS=64
  for (int st = 0; st < nt; ++st){
    const int s0 = st * 64;
    // K fragments straight from global: row s = s0+nf*16+q16, d-chunk 64B-coalesced
    bf16x8 kf[2][4];
    #pragma unroll
    for (int ks = 0; ks < 2; ++ks)
      #pragma unroll
      for (int nf = 0; nf < 4; ++nf)
        kf[ks][nf] = *(const bf16x8*)(K + (size_t)(s0 + nf * 16 + q16) * 1024 + ks * 32 + c4 * 8);
    // S^T = K Q^T for both q-sets (rows=s, cols=q; lane q = l&15)
    f32x4 sf[2][4] = {};
    #pragma unroll
    for (int ks = 0; ks < 2; ++ks)
      #pragma unroll
      for (int nf = 0; nf < 4; ++nf){
        sf[0][nf] = __builtin_amdgcn_mfma_f32_16x16x32_bf16(kf[ks][nf], qf[0][ks], sf[0][nf], 0, 0, 0);
        sf[1][nf] = __builtin_amdgcn_mfma_f32_16x16x32_bf16(kf[ks][nf], qf[1][ks], sf[1][nf], 0, 0, 0);
      }
    // V fragments (issued now, consumed after softmax ~300cy later)
    bf16x8 vf[2][4];
    #pragma unroll
    for (int ks2 = 0; ks2 < 2; ++ks2)
      #pragma unroll
      for (int df = 0; df < 4; ++df)
        vf[ks2][df] = *(const bf16x8*)(Vt + (size_t)(df * 16 + q16) * TT + s0 + ks2 * 32 + c4 * 8);
    // softmax per q-set (scores in log2 domain; Q pre-scaled by LSCALE)
    const bool domask = (st == nt - 1);
    #pragma unroll
    for (int qs = 0; qs < 2; ++qs){
      const int qa = q0 + qs * 16 + q16;
      float p[4][4];
      #pragma unroll
      for (int nf = 0; nf < 4; ++nf)
        #pragma unroll
        for (int r = 0; r < 4; ++r){
          float v_ = sf[qs][nf][r];
          if (domask && (s0 + nf * 16 + c4 * 4 + r > qa)) v_ = -1e30f;
          p[nf][r] = v_;
        }
      float tmax = p[0][0];
      #pragma unroll
      for (int nf = 0; nf < 4; ++nf)
        #pragma unroll
        for (int r = 0; r < 4; ++r) tmax = fmaxf(tmax, p[nf][r]);
      tmax = fmaxf(tmax, __shfl_xor(tmax, 16));
      tmax = fmaxf(tmax, __shfl_xor(tmax, 32));
      if (__any(tmax > mrow[qs] + 8.0f)){
        float mnew = fmaxf(mrow[qs], tmax);
        float resc = exp2f(mrow[qs] - mnew);
        srow[qs] *= resc;
        mrow[qs] = mnew;
        float rq[4];
        #pragma unroll
        for (int r = 0; r < 4; ++r) rq[r] = __shfl(resc, (l & 48) | (c4 * 4 + r));
        #pragma unroll
        for (int df = 0; df < 4; ++df)
          #pragma unroll
          for (int r = 0; r < 4; ++r) yacc[qs][df][r] *= rq[r];
      }
      float tsum = 0.f;
      #pragma unroll
      for (int nf = 0; nf < 4; ++nf)
        #pragma unroll
        for (int r = 0; r < 4; ++r){ float e = exp2f(p[nf][r] - mrow[qs]); p[nf][r] = e; tsum += e; }
      tsum += __shfl_xor(tsum, 16);
      tsum += __shfl_xor(tsum, 32);
      srow[qs] += tsum;
      // pack P -> wave-private LDS row q (XOR-swizzled dword cols)
      uint32_t* dst = (uint32_t*)&Ps[qs][0] + q16 * 32;
      #pragma unroll
      for (int nf = 0; nf < 4; ++nf){
        uint32_t w0, w1;
        asm volatile("v_cvt_pk_bf16_f32 %0, %1, %2" : "=v"(w0) : "v"(p[nf][0]), "v"(p[nf][1]));
        asm volatile("v_cvt_pk_bf16_f32 %0, %1, %2" : "=v"(w1) : "v"(p[nf][2]), "v"(p[nf][3]));
        *(uint64_t*)(dst + ((nf * 8 + c4 * 2) ^ pm)) = (uint64_t)w0 | ((uint64_t)w1 << 32);
      }
    }
    asm volatile("s_waitcnt lgkmcnt(0)" ::: "memory");
    __builtin_amdgcn_sched_barrier(0);
    // PV for both sets: y += P @ V  (A = P rows q; B = V^T rows d)
    #pragma unroll
    for (int qs = 0; qs < 2; ++qs){
      const uint32_t* src = (const uint32_t*)&Ps[qs][0] + q16 * 32;
      #pragma unroll
      for (int ks2 = 0; ks2 < 2; ++ks2){
        bf16x8 pf = *(const bf16x8*)(src + ((ks2 * 16 + c4 * 4) ^ pm));
        #pragma unroll
        for (int df = 0; df < 4; ++df)
          yacc[qs][df] = __builtin_amdgcn_mfma_f32_16x16x32_bf16(pf, vf[ks2][df], yacc[qs][df], 0, 0, 0);
      }
    }
  }
  // epilogue: yacc rows q = 4*c4 + r need srow from lane (l&48)|q
  #pragma unroll
  for (int qs = 0; qs < 2; ++qs){
    float sq[4];
    #pragma unroll
    for (int r = 0; r < 4; ++r) sq[r] = __shfl(srow[qs], (l & 48) | (c4 * 4 + r));
    #pragma unroll
    for (int df = 0; df < 4; ++df){
      int d = df * 16 + q16;
      int qq = q0 + qs * 16 + c4 * 4;
      #pragma unroll
      for (int r = 0; r < 4; ++r){
        float val = yacc[qs][df][r] / sq[r];
        yg[(size_t)(b * TT + qq + r) * 1024 + h * 64 + d] = f2b(val);
      }
    }
  }
}

// ---------------- host ----------------
extern "C" void kernel_launch(void* const* d_in, const int* in_sizes, int n_in,
                              void* d_out, int out_size, void* d_ws, size_t ws_size,
                              hipStream_t stream){
  (void)in_sizes; (void)n_in; (void)out_size; (void)ws_size;
  const float* x  = (const float*)d_in[0];
  const float* Wq = (const float*)d_in[1];
  const float* bq = (const float*)d_in[2];
  const float* Wk = (const float*)d_in[3];
  const float* bk = (const float*)d_in[4];
  const float* Wv = (const float*)d_in[5];
  const float* bv = (const float*)d_in[6];
  const float* Wo = (const float*)d_in[7];
  const float* bo = (const float*)d_in[8];
  const float* Wc = (const float*)d_in[9];
  float* out = (float*)d_out;

  char* wsb = (char*)d_ws;
  // alias plan (stream-ordered): xb dead after gemm_qkv -> yb; Wqcf dead
  // after transpose_w4 -> vtb region.
  u16* xb    = (u16*)(wsb);               //  0..8M
  u16* yb    = (u16*)(wsb);               //  alias xb
  u16* qcb   = (u16*)(wsb + (8u  << 20)); //  8..16M
  u16* kb    = (u16*)(wsb + (16u << 20)); // 16..24M
  u16* vb    = (u16*)(wsb + (24u << 20)); // 24..32M
  u16* vtb   = (u16*)(wsb + (33u << 20)); // 33..41M
  float* Wqcf = (float*)(wsb + (33u << 20)); // alias vtb (dead before vtb written)
  u16* WqcT  = (u16*)(wsb + (42u << 20));
  u16* WkT   = (u16*)(wsb + (44u << 20));
  u16* WvT   = (u16*)(wsb + (46u << 20));
  u16* WoT   = (u16*)(wsb + (48u << 20));
  float* bqc  = (float*)(wsb + (50u << 20));

  cvt_bf16<<<4096, 256, 0, stream>>>(x, xb, MROWS * 1024 / 4);
  build_wqc<<<257, 256, 0, stream>>>(Wq, Wc, bq, Wqcf, bqc);
  transpose_w4<<<dim3(32, 32, 4), 256, 0, stream>>>(Wqcf, Wk, Wv, Wo, WqcT, WkT, WvT, WoT);
  gemm_qkv<<<dim3(8, 32, 3), 256, 0, stream>>>(xb, WqcT, WkT, WvT, bqc, bk, bv, qcb, kb, vb);
  transpose_v<<<dim3(64, 2, 32), 256, 0, stream>>>(vb, vtb);
  attn<<<dim3(2048), 64, 0, stream>>>(qcb, kb, vtb, yb);
  gemm_fp32out<<<dim3(8, 32), 256, 0, stream>>>(yb, WoT, bo, out);
}

// Round 9
// 131.973 us; speedup vs baseline: 1.1894x; 1.1894x over previous
//
#include <hip/hip_runtime.h>
#include <stdint.h>

#define TT 2048
#define BB 2
#define MROWS (BB*TT)
#define LSCALE 0.18033688011112043f   // 0.125 * log2(e)

typedef unsigned short u16;
typedef __bf16 bf16x8 __attribute__((ext_vector_type(8)));
typedef float f32x4 __attribute__((ext_vector_type(4)));
typedef short s16x8 __attribute__((ext_vector_type(8)));
typedef unsigned short u16x4 __attribute__((ext_vector_type(4)));

#define GLOBAL_AS const __attribute__((address_space(1))) void*
#define LDS_AS __attribute__((address_space(3))) void*

__device__ __forceinline__ u16 f2b(float f){
  uint32_t u = __builtin_bit_cast(uint32_t, f);
  u = (u + 0x7FFFu + ((u >> 16) & 1u)) >> 16;
  return (u16)u;
}
__device__ __forceinline__ float b2f(u16 u){
  return __builtin_bit_cast(float, (uint32_t)u << 16);
}

// ---------------- prep kernels ----------------
__global__ void cvt_bf16(const float* __restrict__ in, u16* __restrict__ out, int n4){
  int i = blockIdx.x * 256 + threadIdx.x;
  if (i < n4){
    float4 v = ((const float4*)in)[i];
    u16x4 o; o.x = f2b(v.x); o.y = f2b(v.y); o.z = f2b(v.z); o.w = f2b(v.w);
    ((u16x4*)out)[i] = o;
  }
}

// Wqc[d][h*64+lc] = sum_dd Wq[d][h*64+dd] * Wc[dd][lc]  (fold Wc into Wq)
// block 256 additionally builds bqc (folded bias).
__global__ __launch_bounds__(256) void build_wqc(const float* __restrict__ Wq,
                                                 const float* __restrict__ Wc,
                                                 const float* __restrict__ bq,
                                                 float* __restrict__ Wqc,
                                                 float* __restrict__ bqc){
  __shared__ float wc[4096];
  const int t = threadIdx.x;
  #pragma unroll
  for (int i = 0; i < 16; ++i) wc[i * 256 + t] = Wc[i * 256 + t];
  __syncthreads();
  if (blockIdx.x == 256){
    #pragma unroll
    for (int i = 0; i < 4; ++i){
      int nn = t * 4 + i;
      int h = nn >> 6, lc = nn & 63;
      float acc = 0.f;
      #pragma unroll
      for (int dd = 0; dd < 64; ++dd) acc += bq[h * 64 + dd] * wc[dd * 64 + lc];
      bqc[nn] = acc;
    }
    return;
  }
  const int idx = blockIdx.x * 256 + t;   // [0, 65536)
  const int d = idx >> 6;
  const int h = (idx >> 2) & 15;
  const int lq = idx & 3;
  float wqr[64];
  const float4* wq4 = (const float4*)(Wq + (size_t)d * 1024 + h * 64);
  #pragma unroll
  for (int i = 0; i < 16; ++i){
    float4 v = wq4[i];
    wqr[i * 4 + 0] = v.x; wqr[i * 4 + 1] = v.y; wqr[i * 4 + 2] = v.z; wqr[i * 4 + 3] = v.w;
  }
  float* outp = Wqc + (size_t)d * 1024 + h * 64 + lq * 16;
  #pragma unroll
  for (int j = 0; j < 16; ++j){
    int lc = lq * 16 + j;
    float acc = 0.f;
    #pragma unroll
    for (int dd = 0; dd < 64; ++dd) acc += wqr[dd] * wc[dd * 64 + lc];
    outp[j] = acc;
  }
}

// all four 1024x1024 weight transposes (f32 -> bf16, out[c][r] = in[r][c]) in one dispatch
__global__ void transpose_w4(const float* __restrict__ s0, const float* __restrict__ s1,
                             const float* __restrict__ s2, const float* __restrict__ s3,
                             u16* __restrict__ o0, u16* __restrict__ o1,
                             u16* __restrict__ o2, u16* __restrict__ o3){
  const int z = blockIdx.z;
  const float* in = (z == 0) ? s0 : (z == 1) ? s1 : (z == 2) ? s2 : s3;
  u16* out = (z == 0) ? o0 : (z == 1) ? o1 : (z == 2) ? o2 : o3;
  __shared__ float t[32][33];
  int tx = threadIdx.x & 31, ty = threadIdx.x >> 5;
  int c0 = blockIdx.x * 32, r0 = blockIdx.y * 32;
  #pragma unroll
  for (int i = 0; i < 32; i += 8)
    t[ty + i][tx] = in[(size_t)(r0 + ty + i) * 1024 + c0 + tx];
  __syncthreads();
  #pragma unroll
  for (int i = 0; i < 32; i += 8)
    out[(size_t)(c0 + ty + i) * 1024 + r0 + tx] = f2b(t[tx][ty + i]);
}

// vt[bh][d][s] = vb[b*T + s][h*64 + d]   (bf16 -> bf16 transpose per head)
__global__ void transpose_v(const u16* __restrict__ vb, u16* __restrict__ vt){
  __shared__ u16 t[32][34];
  int tx = threadIdx.x & 31, ty = threadIdx.x >> 5;
  int s0 = blockIdx.x * 32, d0 = blockIdx.y * 32, bh = blockIdx.z;
  int b = bh >> 4, h = bh & 15;
  #pragma unroll
  for (int i = 0; i < 32; i += 8)
    t[ty + i][tx] = vb[(size_t)(b * TT + s0 + ty + i) * 1024 + h * 64 + d0 + tx];
  __syncthreads();
  #pragma unroll
  for (int i = 0; i < 32; i += 8)
    vt[((size_t)bh * 64 + d0 + ty + i) * TT + s0 + tx] = t[tx][ty + i];
}

// ---------------- 128x128 bf16 MFMA GEMM tile (m97 structure) ----------------
__device__ __forceinline__ void gemm_tile(const u16* __restrict__ A, const u16* __restrict__ BT,
                                          int m0, int n0, int K, f32x4 (&acc)[4][4],
                                          u16* As, u16* Bs, int tid){
  const int wv = tid >> 6, l = tid & 63;
  const int aoff = ((wv >> 1) * 64 + (l & 15)) * 32 + ((l >> 4) << 3);
  const int boff = ((wv & 1) * 64 + (l & 15)) * 32 + ((l >> 4) << 3);
  const int ob0 = wv * 1024 + l * 16;           // byte offset in 8KB tile
  for (int kt = 0; kt < K; kt += 32){
    __syncthreads();
    #pragma unroll
    for (int j = 0; j < 2; ++j){
      int ob = ob0 + j * 4096;
      int row = ob >> 6, col = (ob & 63) >> 1;  // col in elements (mult of 8)
      __builtin_amdgcn_global_load_lds((GLOBAL_AS)(A + (size_t)(m0 + row) * 1024 + kt + col),
                                       (LDS_AS)(As + wv * 512 + j * 2048), 16, 0, 0);
      __builtin_amdgcn_global_load_lds((GLOBAL_AS)(BT + (size_t)(n0 + row) * 1024 + kt + col),
                                       (LDS_AS)(Bs + wv * 512 + j * 2048), 16, 0, 0);
    }
    __syncthreads();
    bf16x8 av[4], bw[4];
    #pragma unroll
    for (int m = 0; m < 4; ++m) av[m] = *(const bf16x8*)(As + aoff + m * 512);
    #pragma unroll
    for (int n = 0; n < 4; ++n) bw[n] = *(const bf16x8*)(Bs + boff + n * 512);
    #pragma unroll
    for (int m = 0; m < 4; ++m)
      #pragma unroll
      for (int n = 0; n < 4; ++n)
        acc[m][n] = __builtin_amdgcn_mfma_f32_16x16x32_bf16(av[m], bw[n], acc[m][n], 0, 0, 0);
  }
}

__global__ __launch_bounds__(256) void gemm_qkv(
    const u16* __restrict__ xb,
    const u16* __restrict__ W0T, const u16* __restrict__ W1T, const u16* __restrict__ W2T,
    const float* __restrict__ b0, const float* __restrict__ b1, const float* __restrict__ b2,
    u16* __restrict__ o0, u16* __restrict__ o1, u16* __restrict__ o2){
  __shared__ u16 As[4096], Bs[4096];
  const int z = blockIdx.z;
  const u16* BT = (z == 0) ? W0T : (z == 1) ? W1T : W2T;
  const float* bias = (z == 0) ? b0 : (z == 1) ? b1 : b2;
  u16* Out = (z == 0) ? o0 : (z == 1) ? o1 : o2;
  const float osc = (z == 0) ? LSCALE : 1.0f;   // fold softmax scale into Q
  const int n0 = blockIdx.x * 128, m0 = blockIdx.y * 128;
  const int tid = threadIdx.x, wv = tid >> 6, l = tid & 63;
  f32x4 acc[4][4] = {};
  gemm_tile(xb, BT, m0, n0, 1024, acc, As, Bs, tid);
  const int wr = wv >> 1, wc = wv & 1;
  #pragma unroll
  for (int n = 0; n < 4; ++n){
    int col = n0 + wc * 64 + n * 16 + (l & 15);
    float bb = bias[col];
    #pragma unroll
    for (int m = 0; m < 4; ++m){
      int r0 = m0 + wr * 64 + m * 16 + ((l >> 4) << 2);
      #pragma unroll
      for (int r = 0; r < 4; ++r)
        Out[(size_t)(r0 + r) * 1024 + col] = f2b((acc[m][n][r] + bb) * osc);
    }
  }
}

__global__ __launch_bounds__(256) void gemm_fp32out(
    const u16* __restrict__ A, const u16* __restrict__ BT,
    const float* __restrict__ bias, float* __restrict__ Out){
  __shared__ u16 As[4096], Bs[4096];
  const int n0 = blockIdx.x * 128, m0 = blockIdx.y * 128;
  const int tid = threadIdx.x, wv = tid >> 6, l = tid & 63;
  f32x4 acc[4][4] = {};
  gemm_tile(A, BT, m0, n0, 1024, acc, As, Bs, tid);
  const int wr = wv >> 1, wc = wv & 1;
  #pragma unroll
  for (int n = 0; n < 4; ++n){
    int col = n0 + wc * 64 + n * 16 + (l & 15);
    float bb = bias[col];
    #pragma unroll
    for (int m = 0; m < 4; ++m){
      int r0 = m0 + wr * 64 + m * 16 + ((l >> 4) << 2);
      #pragma unroll
      for (int r = 0; r < 4; ++r)
        Out[(size_t)(r0 + r) * 1024 + col] = acc[m][n][r] + bb;
    }
  }
}

// ---------------- flash attention (causal, per (b,h)) ----------------
// BQ=64 (4 waves x 16 q-rows), BS=64. SINGLE-buffer K/V staging (24KB LDS
// total -> 6 blocks/CU); exposed per-tile vmcnt hidden by 6-way block TLP.
// PV computes y^T = mfma(V^T, P) so softmax state q is LANE-LOCAL (no
// rescale/normalize shuffles). Chains qt>=16 split in 2 (R6 gtab, verified);
// bh = idx&31 keeps 4 heads per XCD (L2-resident K/V).
__device__ const uint8_t gtab[48] = {
  31, 95, 30, 143,  94, 29, 93, 28, 142,  92, 27, 91, 26, 141,
  90, 25, 89, 24, 140,  88, 23, 87, 22, 139,  86, 21, 85, 20, 138,
  84, 19, 83, 18, 137,  82, 17, 81, 16, 136,  80, 135, 134, 133, 132,
  131, 130, 129, 128
};

__global__ __launch_bounds__(256) void attn(
    const u16* __restrict__ qcg, const u16* __restrict__ kg,
    const u16* __restrict__ vtg, u16* __restrict__ yg,
    u16* __restrict__ yp, float* __restrict__ mp, float* __restrict__ lp){
  __shared__ u16 Ks[4096], Vs[4096];   // [64 rows][8 chunks of 16B], XOR-swizzled
  __shared__ u16 Ps[4096];             // per-wave 16 q-rows x 64 s, XOR-swizzled dwords
  const int idx = blockIdx.x;
  const int g = idx >> 5, bh = idx & 31;
  const int gv_ = gtab[g];
  const int qt = gv_ & 31, piece = gv_ >> 6;
  const int hh = (qt + 2) >> 1;
  const int st0 = (piece == 1) ? hh : 0;
  const int st1 = (piece == 0) ? hh : qt + 1;
  const int pid = (piece == 2) ? -1 : ((31 - qt) * 32 + bh) * 2 + piece;
  const int b = bh >> 4, h = bh & 15;
  const int q0 = qt * 64;
  const int tid = threadIdx.x, wv = tid >> 6, l = tid & 63;
  const int c4 = l >> 4, q16 = l & 15;
  const size_t base = (size_t)b * TT * 1024 + h * 64;
  const u16* Q = qcg + base;
  const u16* K = kg + base;
  const u16* Vt = vtg + (size_t)bh * 64 * TT;     // [64 d][T s]

  // staging source (pre-swizzled so linear LDS == swizzled layout, m173 pattern)
  const int sr = tid >> 3;                         // tile row 0..31 (x2 halves)
  const int sc = (tid & 7) ^ (sr & 7);             // global 16B-chunk for this slot
  const u16* gK = K + (size_t)sr * 1024 + sc * 8;
  const u16* gV = Vt + (size_t)sr * TT + sc * 8;

  // Q fragments in registers: 16 q-rows per wave (B-operand: col=q at l&15)
  bf16x8 qf[2];
  {
    int qr = q0 + wv * 16 + q16;
    #pragma unroll
    for (int ks = 0; ks < 2; ++ks)
      qf[ks] = *(const bf16x8*)(Q + (size_t)qr * 1024 + ks * 32 + (c4 << 3));
  }
  f32x4 yacc[4] = {};                  // y^T: yacc[df][r] = y[q=q16][d=df*16+c4*4+r]
  float mrow = -1e30f, srow = 0.f;     // per-lane softmax state for q = l&15

  uint32_t* const PsW = (uint32_t*)Ps + wv * 512 + q16 * 32;  // this lane's P row (dwords)
  const int pm = (q16 & 7) << 2;                              // Ps dword-col XOR mask

  u16* const kd = Ks + wv * 512;
  u16* const vd = Vs + wv * 512;

  for (int st = st0; st < st1; ++st){
    // stage tile st (single buffer; prev tile's readers retired at loop-end barrier)
    {
      const size_t o = (size_t)st * 64;
      __builtin_amdgcn_global_load_lds((GLOBAL_AS)(gK + o * 1024), (LDS_AS)kd, 16, 0, 0);
      __builtin_amdgcn_global_load_lds((GLOBAL_AS)(gK + (o + 32) * 1024), (LDS_AS)(kd + 2048), 16, 0, 0);
      __builtin_amdgcn_global_load_lds((GLOBAL_AS)(gV + o), (LDS_AS)vd, 16, 0, 0);
      __builtin_amdgcn_global_load_lds((GLOBAL_AS)(gV + o + 32 * TT), (LDS_AS)(vd + 2048), 16, 0, 0);
    }
    asm volatile("s_waitcnt vmcnt(0)" ::: "memory");
    __builtin_amdgcn_sched_barrier(0);
    __builtin_amdgcn_s_barrier();                 // all waves' staging landed
    __builtin_amdgcn_sched_barrier(0);
    const int s0 = st * 64;
    // S^T = K Q^T  (rows=s, cols=q): lane holds 16 s-values for q = l&15
    f32x4 sf[4] = {};
    __builtin_amdgcn_s_setprio(1);
    #pragma unroll
    for (int ks = 0; ks < 2; ++ks)
      #pragma unroll
      for (int nf = 0; nf < 4; ++nf){
        int r = nf * 16 + q16, c = ks * 4 + c4;
        bf16x8 kf = *(const bf16x8*)(Ks + (r * 8 + (c ^ (r & 7))) * 8);
        sf[nf] = __builtin_amdgcn_mfma_f32_16x16x32_bf16(kf, qf[ks], sf[nf], 0, 0, 0);
      }
    __builtin_amdgcn_s_setprio(0);
    // causal mask (diagonal tile only); scores already in log2 domain (Q pre-scaled)
    const int qa = q0 + wv * 16 + q16;
    float p[4][4];
    const bool domask = (st == qt);
    #pragma unroll
    for (int nf = 0; nf < 4; ++nf)
      #pragma unroll
      for (int r = 0; r < 4; ++r){
        float v_ = sf[nf][r];
        if (domask && (s0 + nf * 16 + c4 * 4 + r > qa)) v_ = -1e30f;
        p[nf][r] = v_;
      }
    // lane-local row max + quadrant combine
    float tmax = p[0][0];
    #pragma unroll
    for (int nf = 0; nf < 4; ++nf)
      #pragma unroll
      for (int r = 0; r < 4; ++r) tmax = fmaxf(tmax, p[nf][r]);
    tmax = fmaxf(tmax, __shfl_xor(tmax, 16));
    tmax = fmaxf(tmax, __shfl_xor(tmax, 32));
    // defer-max: rescale only when max grew by > 8 (factor 256 headroom)
    if (__any(tmax > mrow + 8.0f)){
      float mnew = fmaxf(mrow, tmax);
      float resc = exp2f(mrow - mnew);
      srow *= resc;
      mrow = mnew;
      #pragma unroll
      for (int df = 0; df < 4; ++df)
        #pragma unroll
        for (int r = 0; r < 4; ++r) yacc[df][r] *= resc;   // q lane-local: no shuffle
    }
    float tsum = 0.f;
    #pragma unroll
    for (int nf = 0; nf < 4; ++nf)
      #pragma unroll
      for (int r = 0; r < 4; ++r){ float e = exp2f(p[nf][r] - mrow); p[nf][r] = e; tsum += e; }
    tsum += __shfl_xor(tsum, 16);
    tsum += __shfl_xor(tsum, 32);
    srow += tsum;
    // pack P (pairs along s) -> wave-private LDS row q, XOR-swizzled dword cols
    #pragma unroll
    for (int nf = 0; nf < 4; ++nf){
      uint32_t w0, w1;
      asm volatile("v_cvt_pk_bf16_f32 %0, %1, %2" : "=v"(w0) : "v"(p[nf][0]), "v"(p[nf][1]));
      asm volatile("v_cvt_pk_bf16_f32 %0, %1, %2" : "=v"(w1) : "v"(p[nf][2]), "v"(p[nf][3]));
      *(uint64_t*)(PsW + ((nf * 8 + c4 * 2) ^ pm)) = (uint64_t)w0 | ((uint64_t)w1 << 32);
    }
    asm volatile("s_waitcnt lgkmcnt(0)" ::: "memory");
    __builtin_amdgcn_sched_barrier(0);
    // PV swapped: y^T += V^T P  (A = V^T rows d from LDS; B = P cols q=l&15)
    __builtin_amdgcn_s_setprio(1);
    #pragma unroll
    for (int ks2 = 0; ks2 < 2; ++ks2){
      bf16x8 pf = *(const bf16x8*)(PsW + ((ks2 * 16 + c4 * 4) ^ pm));
      #pragma unroll
      for (int df = 0; df < 4; ++df){
        int rd = df * 16 + q16, cd = ks2 * 4 + c4;
        bf16x8 vf = *(const bf16x8*)(Vs + (rd * 8 + (cd ^ (rd & 7))) * 8);
        yacc[df] = __builtin_amdgcn_mfma_f32_16x16x32_bf16(vf, pf, yacc[df], 0, 0, 0);
      }
    }
    __builtin_amdgcn_s_setprio(0);
    __builtin_amdgcn_s_barrier();                 // all waves done reading Ks/Vs
  }

  if (pid >= 0){
    // unnormalized partial: yp[pid][q][d] (bf16), q = wv*16+q16 lane-local
    const int qq = wv * 16 + q16;
    #pragma unroll
    for (int df = 0; df < 4; ++df){
      int d0 = df * 16 + c4 * 4;
      #pragma unroll
      for (int r = 0; r < 4; ++r)
        yp[(size_t)pid * 4096 + qq * 64 + d0 + r] = f2b(yacc[df][r]);
    }
    if (c4 == 0){
      mp[pid * 64 + qq] = mrow;
      lp[pid * 64 + qq] = srow;
    }
  } else {
    // final: y[q][d] = yacc/srow, all lane-local
    const float inv = 1.f / srow;
    const int qq = q0 + wv * 16 + q16;
    #pragma unroll
    for (int df = 0; df < 4; ++df){
      int d0 = df * 16 + c4 * 4;
      #pragma unroll
      for (int r = 0; r < 4; ++r)
        yg[(size_t)(b * TT + qq) * 1024 + h * 64 + d0 + r] = f2b(yacc[df][r] * inv);
    }
  }
}

// merge the two partials of each split (qt,bh) -> yg.  cid = blockIdx.x:
// qt = 31-(cid>>5), bh = cid&31, pid0 = cid*2.
__global__ __launch_bounds__(256) void attn_combine(
    const u16* __restrict__ yp, const float* __restrict__ mp, const float* __restrict__ lp,
    u16* __restrict__ yg){
  const int cid = blockIdx.x;                  // 0..511
  const int qt = 31 - (cid >> 5), bh = cid & 31;
  const int pid0 = cid * 2;
  const int t = threadIdx.x;
  const int q = t >> 2, dc = (t & 3) * 16;
  float m1 = mp[pid0 * 64 + q], m2 = mp[(pid0 + 1) * 64 + q];
  float l1 = lp[pid0 * 64 + q], l2 = lp[(pid0 + 1) * 64 + q];
  float ms = fmaxf(m1, m2);
  float w1 = exp2f(m1 - ms), w2 = exp2f(m2 - ms);
  float inv = 1.f / (l1 * w1 + l2 * w2);
  w1 *= inv; w2 *= inv;
  const int b = bh >> 4, h = bh & 15;
  const s16x8* p1 = (const s16x8*)(yp + (size_t)pid0 * 4096 + q * 64 + dc);
  const s16x8* p2 = (const s16x8*)(yp + (size_t)(pid0 + 1) * 4096 + q * 64 + dc);
  u16* dst = yg + (size_t)(b * TT + qt * 64 + q) * 1024 + h * 64 + dc;
  #pragma unroll
  for (int j2 = 0; j2 < 2; ++j2){
    s16x8 a = p1[j2], c = p2[j2];
    s16x8 o;
    #pragma unroll
    for (int j = 0; j < 8; ++j)
      o[j] = (short)f2b(b2f((u16)a[j]) * w1 + b2f((u16)c[j]) * w2);
    *(s16x8*)(dst + j2 * 8) = o;
  }
}

// ---------------- host ----------------
extern "C" void kernel_launch(void* const* d_in, const int* in_sizes, int n_in,
                              void* d_out, int out_size, void* d_ws, size_t ws_size,
                              hipStream_t stream){
  (void)in_sizes; (void)n_in; (void)out_size; (void)ws_size;
  const float* x  = (const float*)d_in[0];
  const float* Wq = (const float*)d_in[1];
  const float* bq = (const float*)d_in[2];
  const float* Wk = (const float*)d_in[3];
  const float* bk = (const float*)d_in[4];
  const float* Wv = (const float*)d_in[5];
  const float* bv = (const float*)d_in[6];
  const float* Wo = (const float*)d_in[7];
  const float* bo = (const float*)d_in[8];
  const float* Wc = (const float*)d_in[9];
  float* out = (float*)d_out;

  char* wsb = (char*)d_ws;
  // alias plan (stream-ordered): xb dead after gemm_qkv -> yb; vb dead after
  // transpose_v -> yp; Wqcf dead after transpose_w4 -> vtb region.
  u16* xb    = (u16*)(wsb);               //  0..8M
  u16* yb    = (u16*)(wsb);               //  alias xb
  u16* qcb   = (u16*)(wsb + (8u  << 20)); //  8..16M
  u16* kb    = (u16*)(wsb + (16u << 20)); // 16..24M
  u16* vb    = (u16*)(wsb + (24u << 20)); // 24..32M (8M)
  u16* yp    = (u16*)(wsb + (24u << 20)); // alias vb: 24..32M (8M: 1024 pids x 8KB)
  u16* vtb   = (u16*)(wsb + (33u << 20)); // 33..41M
  float* Wqcf = (float*)(wsb + (33u << 20)); // alias vtb (dead before vtb written)
  float* mp  = (float*)(wsb + (41u << 20));            // 41M + 256KB
  float* lp  = (float*)(wsb + (41u << 20) + (1u<<19)); // +256KB
  u16* WqcT  = (u16*)(wsb + (42u << 20));
  u16* WkT   = (u16*)(wsb + (44u << 20));
  u16* WvT   = (u16*)(wsb + (46u << 20));
  u16* WoT   = (u16*)(wsb + (48u << 20));
  float* bqc  = (float*)(wsb + (50u << 20));

  cvt_bf16<<<4096, 256, 0, stream>>>(x, xb, MROWS * 1024 / 4);
  build_wqc<<<257, 256, 0, stream>>>(Wq, Wc, bq, Wqcf, bqc);
  transpose_w4<<<dim3(32, 32, 4), 256, 0, stream>>>(Wqcf, Wk, Wv, Wo, WqcT, WkT, WvT, WoT);
  gemm_qkv<<<dim3(8, 32, 3), 256, 0, stream>>>(xb, WqcT, WkT, WvT, bqc, bk, bv, qcb, kb, vb);
  transpose_v<<<dim3(64, 2, 32), 256, 0, stream>>>(vb, vtb);
  attn<<<dim3(1536), 256, 0, stream>>>(qcb, kb, vtb, yb, yp, mp, lp);
  attn_combine<<<dim3(512), 256, 0, stream>>>(yp, mp, lp, yb);
  gemm_fp32out<<<dim3(8, 32), 256, 0, stream>>>(yb, WoT, bo, out);
}